// Round 4
// baseline (678.456 us; speedup 1.0000x reference)
//
#include <hip/hip_runtime.h>

// MovementPrunedLinear R7: fused single-pass GEMM.
// - prep conversion pass ELIMINATED: mpl_fused stages f32 X/W directly,
//   converts with v_cvt_pk_bf16_f32 in regs, ds_write_b64 into the same
//   XOR-swizzled LDS layout (write-XOR == read-XOR; reads measured 0 conflicts).
// - R3's proven single-buffer 2-barrier skeleton (R5/R6 pipeline reverted:
//   242->300us loss, occupancy+sched cost > prefetch gain).
// - 2D x-fastest grid kept (XCD k owns B-cols {k,k+8,k+16,k+24}: L2-resident).
// - masked nb pairs: staging rounds AND MFMAs bit-gated (block-uniform).
// - only a 32-block mask-pack kernel precedes the GEMM.

#define BM 128
#define BN 128
#define BK 64

typedef __attribute__((ext_vector_type(8))) short bf16x8;
typedef __attribute__((ext_vector_type(4))) float f32x4;

__device__ __forceinline__ unsigned short f2bf(float f) {
    union { float f; unsigned u; } v; v.f = f;
    return (unsigned short)((v.u + 0x7FFFu + ((v.u >> 16) & 1u)) >> 16);
}

__device__ __forceinline__ unsigned cvtpk(float lo, float hi) {
    unsigned r;
    asm("v_cvt_pk_bf16_f32 %0, %1, %2" : "=v"(r) : "v"(lo), "v"(hi));
    return r;
}

#define THRESH (-2.1972245773362196f)   // logit(0.1)

// ---------------- mask pack (tiny): 4 nb per block, one per wave ----------------
__global__ __launch_bounds__(256)
void packmask(const float* __restrict__ scores, unsigned long long* __restrict__ mbits,
              int KBlk) {
    const int nb = blockIdx.x * 4 + (threadIdx.x >> 6);
    const int l  = threadIdx.x & 63;
    const unsigned long long b0 = __ballot(scores[(long)nb * KBlk + l] > THRESH);
    const unsigned long long b1 = __ballot(scores[(long)nb * KBlk + 64 + l] > THRESH);
    if (l == 0) { mbits[nb * 2] = b0; mbits[nb * 2 + 1] = b1; }
}

// ---------------- fused main GEMM ----------------

__device__ __forceinline__ unsigned long long rfl64(unsigned long long v) {
    unsigned lo = __builtin_amdgcn_readfirstlane((unsigned)v);
    unsigned hi = __builtin_amdgcn_readfirstlane((unsigned)(v >> 32));
    return ((unsigned long long)hi << 32) | lo;
}

// pair bits (2 bits = k32 blocks 2s,2s+1) for nb-slot i at K-step s
#define PB(i, s) ((unsigned)((((s) & 32) ? mhi[i] : mlo[i]) >> (2 * ((s) & 31))) & 3)

__global__ __launch_bounds__(256)
void mpl_fused(const float* __restrict__ X,     // [M,K] f32
               const float* __restrict__ W,     // [N,K] f32
               const float* __restrict__ bias,
               const unsigned long long* __restrict__ mb, // [N/32][2]
               float* __restrict__ out, int M, int N, int K)
{
    // LDS layout identical to R3: row r = 128 B (BK=64 bf16) in 8 chunks of
    // 16 B; slot (r, c') holds global chunk c' ^ (r&7).
    __shared__ unsigned short sA[BM * BK];   // 16 KB
    __shared__ unsigned short sB[BN * BK];   // 16 KB

    const int tid  = threadIdx.x;
    const int lane = tid & 63;
    const int wave = tid >> 6;
    const int m0   = blockIdx.y * BM;
    const int n0   = blockIdx.x * BN;
    const int wm   = (wave & 1) * 64;
    const int wn   = (wave >> 1) * 64;

    // per-nb mask words (scalarized)
    const int nbb = n0 >> 5;
    unsigned long long mlo[4], mhi[4];
#pragma unroll
    for (int i = 0; i < 4; i++) {
        mlo[i] = rfl64(mb[(nbb + i) * 2]);
        mhi[i] = rfl64(mb[(nbb + i) * 2 + 1]);
    }

    f32x4 acc[4][4];
#pragma unroll
    for (int i = 0; i < 4; i++)
#pragma unroll
        for (int j = 0; j < 4; j++)
            acc[i][j] = (f32x4){0.f, 0.f, 0.f, 0.f};

    // staging geometry: per round, 256 threads cover 16 rows x 16 f32-granules
    // (16 B each). rl = row-in-16, g = granule. bf16 dest of granule g is 8 B
    // at chunk c=g>>1, half g&1, XOR-swizzled by row&7 (= rl&7, loop-invariant).
    const int rl  = tid >> 4;      // 0..15
    const int g   = tid & 15;      // 0..15
    const float* pa = X + (long)(m0 + rl) * K + g * 4;
    const float* pb = W + (long)(n0 + rl) * K + g * 4;
    const int swz = ((((g >> 1) ^ (rl & 7)) << 4) | ((g & 1) << 3));
    char* lA = (char*)sA + rl * 128 + swz;
    char* lB = (char*)sB + rl * 128 + swz;
    char* sAc = (char*)sA;
    char* sBc = (char*)sB;

    // fragment geometry
    const int fr   = lane & 15;
    const int cxor = lane & 7;
    const int kqc  = lane >> 4;          // 0..3
    const int rowA = wm + fr;            // + mi*16
    const int rowB = wn + fr;            // + ni*16

    for (int s = 0; s < 64; ++s) {
        const unsigned c0 = PB(0, s), c1 = PB(1, s), c2 = PB(2, s), c3 = PB(3, s);
        if (!(c0 | c1 | c2 | c3)) continue;   // uniform across block

        const int ks = s * 64;
        // A staging: 8 rounds of 16 rows (f32 load -> cvt_pk -> ds_write_b64)
#pragma unroll
        for (int i = 0; i < 8; i++) {
            const float4 v = *(const float4*)(pa + (long)i * 16 * K + ks);
            uint2 u; u.x = cvtpk(v.x, v.y); u.y = cvtpk(v.z, v.w);
            *(uint2*)(lA + i * 2048) = u;
        }
        // B staging: round j covers rows 16j..16j+15 -> nb j>>1; skip masked
#pragma unroll
        for (int j = 0; j < 8; j++) {
            const unsigned pj = (j >> 1) == 0 ? c0 : (j >> 1) == 1 ? c1
                              : (j >> 1) == 2 ? c2 : c3;
            if (pj) {
                const float4 v = *(const float4*)(pb + (long)j * 16 * K + ks);
                uint2 u; u.x = cvtpk(v.x, v.y); u.y = cvtpk(v.z, v.w);
                *(uint2*)(lB + j * 2048) = u;
            }
        }
        __syncthreads();

        const unsigned plo = (wave >> 1) ? c2 : c0;   // this wave's nb for ni 0,1
        const unsigned phi = (wave >> 1) ? c3 : c1;   // ni 2,3

        if (plo | phi) {
#pragma unroll
            for (int kbl = 0; kbl < 2; ++kbl) {
                if (!(((plo | phi) >> kbl) & 1)) continue;
                const int boff = ((kqc | (kbl << 2)) ^ cxor) * 16;

                bf16x8 af[4];
#pragma unroll
                for (int mi = 0; mi < 4; mi++)
                    af[mi] = *(const bf16x8*)(sAc + (rowA + mi * 16) * 128 + boff);

                if ((plo >> kbl) & 1) {
                    const bf16x8 bf0 = *(const bf16x8*)(sBc + (rowB + 0)  * 128 + boff);
                    const bf16x8 bf1 = *(const bf16x8*)(sBc + (rowB + 16) * 128 + boff);
#pragma unroll
                    for (int mi = 0; mi < 4; mi++) {
                        acc[mi][0] = __builtin_amdgcn_mfma_f32_16x16x32_bf16(af[mi], bf0, acc[mi][0], 0, 0, 0);
                        acc[mi][1] = __builtin_amdgcn_mfma_f32_16x16x32_bf16(af[mi], bf1, acc[mi][1], 0, 0, 0);
                    }
                }
                if ((phi >> kbl) & 1) {
                    const bf16x8 bf2 = *(const bf16x8*)(sBc + (rowB + 32) * 128 + boff);
                    const bf16x8 bf3 = *(const bf16x8*)(sBc + (rowB + 48) * 128 + boff);
#pragma unroll
                    for (int mi = 0; mi < 4; mi++) {
                        acc[mi][2] = __builtin_amdgcn_mfma_f32_16x16x32_bf16(af[mi], bf2, acc[mi][2], 0, 0, 0);
                        acc[mi][3] = __builtin_amdgcn_mfma_f32_16x16x32_bf16(af[mi], bf3, acc[mi][3], 0, 0, 0);
                    }
                }
            }
        }
        __syncthreads();
    }

    // epilogue: C/D col=lane&15 (n), row=(lane>>4)*4+reg (m)
    const int cn = lane & 15;
    const int rq = (lane >> 4) * 4;
#pragma unroll
    for (int ni = 0; ni < 4; ni++) {
        const int n = n0 + wn + ni * 16 + cn;
        const float b = bias[n];
#pragma unroll
        for (int mi = 0; mi < 4; mi++) {
#pragma unroll
            for (int r = 0; r < 4; r++) {
                const int m = m0 + wm + mi * 16 + rq + r;
                out[(long)m * N + n] = acc[mi][ni][r] + b;
            }
        }
    }
}

// ---------------- fallback (R1 kernel) ----------------

#define FBK 32
#define LDSS (FBK + 8)
__global__ __launch_bounds__(256, 2)
void mpl_gemm_fb(const float* __restrict__ X, const float* __restrict__ W,
                 const float* __restrict__ bias, const float* __restrict__ scores,
                 float* __restrict__ out, int M, int N, int K)
{
    __shared__ unsigned short sA[BM * LDSS];
    __shared__ unsigned short sB[BN * LDSS];
    const int tid = threadIdx.x;
    const int m0 = blockIdx.y * BM, n0 = blockIdx.x * BN;
    const int wave = tid >> 6, lane = tid & 63;
    const int wm = (wave & 1) * 64, wn = (wave >> 1) * 64;
    const int kblocks = K >> 5;
    f32x4 acc[4][4];
#pragma unroll
    for (int i = 0; i < 4; i++)
#pragma unroll
        for (int j = 0; j < 4; j++) acc[i][j] = (f32x4){0.f,0.f,0.f,0.f};
    int srow[4], sc4[4], snb[4];
#pragma unroll
    for (int i = 0; i < 4; i++) {
        int f = tid + 256 * i;
        srow[i] = f >> 3; sc4[i] = f & 7; snb[i] = (n0 + srow[i]) >> 5;
    }
    for (int k0 = 0; k0 < K; k0 += FBK) {
        const int kb = k0 >> 5;
#pragma unroll
        for (int i = 0; i < 4; i++) {
            const float4 v = *(const float4*)(X + (long)(m0 + srow[i]) * K + k0 + sc4[i] * 4);
            ushort4 p; p.x = f2bf(v.x); p.y = f2bf(v.y); p.z = f2bf(v.z); p.w = f2bf(v.w);
            *(ushort4*)&sA[srow[i] * LDSS + sc4[i] * 4] = p;
        }
#pragma unroll
        for (int i = 0; i < 4; i++) {
            const float msk = (scores[snb[i] * kblocks + kb] > THRESH) ? 1.0f : 0.0f;
            const float4 v = *(const float4*)(W + (long)(n0 + srow[i]) * K + k0 + sc4[i] * 4);
            ushort4 p; p.x = f2bf(v.x*msk); p.y = f2bf(v.y*msk); p.z = f2bf(v.z*msk); p.w = f2bf(v.w*msk);
            *(ushort4*)&sB[srow[i] * LDSS + sc4[i] * 4] = p;
        }
        __syncthreads();
        const int fr = lane & 15, kq = (lane >> 4) * 8;
        bf16x8 af[4], bfr[4];
#pragma unroll
        for (int mi = 0; mi < 4; mi++) af[mi] = *(const bf16x8*)&sA[(wm + mi*16 + fr) * LDSS + kq];
#pragma unroll
        for (int ni = 0; ni < 4; ni++) bfr[ni] = *(const bf16x8*)&sB[(wn + ni*16 + fr) * LDSS + kq];
#pragma unroll
        for (int mi = 0; mi < 4; mi++)
#pragma unroll
            for (int ni = 0; ni < 4; ni++)
                acc[mi][ni] = __builtin_amdgcn_mfma_f32_16x16x32_bf16(af[mi], bfr[ni], acc[mi][ni], 0,0,0);
        __syncthreads();
    }
    const int cn = lane & 15, rq = (lane >> 4) * 4;
#pragma unroll
    for (int ni = 0; ni < 4; ni++) {
        const int n = n0 + wn + ni * 16 + cn;
        const float b = bias[n];
#pragma unroll
        for (int mi = 0; mi < 4; mi++)
#pragma unroll
            for (int r = 0; r < 4; r++)
                out[(long)(m0 + wm + mi*16 + rq + r) * N + n] = acc[mi][ni][r] + b;
    }
}

extern "C" void kernel_launch(void* const* d_in, const int* in_sizes, int n_in,
                              void* d_out, int out_size, void* d_ws, size_t ws_size,
                              hipStream_t stream) {
    const float* X      = (const float*)d_in[0];
    const float* W      = (const float*)d_in[1];
    const float* bias   = (const float*)d_in[2];
    const float* scores = (const float*)d_in[3];
    float* out          = (float*)d_out;

    const int N = in_sizes[2];            // 4096
    const int K = in_sizes[1] / N;        // 4096
    const int M = in_sizes[0] / K;        // 8192
    const int KB = K >> 5;                // 128
    const int NB = N >> 5;                // 128

    const size_t need = (size_t)NB * 16;

    if (ws_size >= need && KB == 128 && (M % 128) == 0 && (N % 128) == 0 &&
        (NB % 4) == 0) {
        unsigned long long* mbits = (unsigned long long*)d_ws;

        packmask<<<NB / 4, 256, 0, stream>>>(scores, mbits, KB);

        dim3 grid(N / BN, M / BM);
        mpl_fused<<<grid, dim3(256), 0, stream>>>(X, W, bias, mbits, out, M, N, K);
    } else {
        dim3 grid(N / BN, M / BM);
        mpl_gemm_fb<<<grid, dim3(256), 0, stream>>>(X, W, bias, scores, out, M, N, K);
    }
}

// Round 6
// 502.267 us; speedup vs baseline: 1.3508x; 1.3508x over previous
//
#include <hip/hip_runtime.h>

// MovementPrunedLinear R9: race-free 256^2 2-phase counted-vmcnt GEMM.
// R8's absmax failure root-caused: stages targeted LDS regions being read in the
// SAME phase (no barrier between another wave's GLL-write landing and this
// wave's ds_read). Fix: B fragments read once in phase 0 and kept in REGISTERS
// across both phases, so the read map is phase0={k0,k2,k3}, phase1={k1}; every
// stage now targets a region whose last reads completed in an earlier phase:
//   phase0(t): stage (t+1).k1  (buf^1; k1/buf^1 last read phase1(t-1))
//   phase1(t): stage (t+2).k0,k2,k3 (buf; those regions last read phase0(t))
// vmcnt ledger (per wave, 2 loads per STAGEH, issue order fixed):
//   prologue: t0 all(8) + t1.k0k2k3(6) -> vmcnt(6) ensures t0 landed
//   phase0(t): after stage, outstanding newest 8 = (t+1).k1 + (t+1).k0k2k3
//              -> vmcnt(8) ensures (t).k1 landed (read next phase)
//   phase1(t): newest 8 = (t+2).k0k2k3 + (t+1).k1 -> vmcnt(8) ensures
//              (t+1).k0k2k3 landed (read next phase). Tail: 8 -> 2 -> 0.
// Mask gating unchanged: B stages unconditional (uniform vmcnt), ds-reads and
// MFMAs gated per wave's 2nb x 2kk bits. Grid x-fastest (B-panel L2/XCD).

typedef __attribute__((ext_vector_type(8))) short bf16x8;
typedef __attribute__((ext_vector_type(4))) float f32x4;

__device__ __forceinline__ unsigned short f2bf(float f) {
    union { float f; unsigned u; } v; v.f = f;
    return (unsigned short)((v.u + 0x7FFFu + ((v.u >> 16) & 1u)) >> 16);
}

#define THRESH (-2.1972245773362196f)   // logit(0.1)

// ---------------- merged pre-pass (grid-stride, R4-proven) ----------------
__global__ __launch_bounds__(256)
void prep(const float* __restrict__ X, const float* __restrict__ W,
          const float* __restrict__ scores,
          unsigned short* __restrict__ Xb, unsigned short* __restrict__ Wb,
          unsigned long long* __restrict__ mbits,
          int M, int N, int K) {
    const int b   = blockIdx.x;
    const int tid = threadIdx.x;
    const int KBlk = K >> 5;

    if (b < 2048) {
        for (int row = b; row < M; row += 2048) {
            const float* src = X + (long)row * K;
            unsigned short* dst = Xb + (long)row * K;
            for (int k = tid * 4; k < K; k += 1024) {
                const float4 a = *(const float4*)(src + k);
                ushort4 p;
                p.x = f2bf(a.x); p.y = f2bf(a.y); p.z = f2bf(a.z); p.w = f2bf(a.w);
                *(ushort4*)(dst + k) = p;
            }
        }
    } else if (b < 3072) {
        for (int row = b - 2048; row < N; row += 1024) {
            const float* src = W + (long)row * K;
            unsigned short* dst = Wb + (long)row * K;
            const float* srow = scores + (long)(row >> 5) * KBlk;
            for (int k = tid * 4; k < K; k += 1024) {
                if (srow[k >> 5] > THRESH) {          // uniform across 8-lane groups
                    const float4 a = *(const float4*)(src + k);
                    ushort4 p;
                    p.x = f2bf(a.x); p.y = f2bf(a.y); p.z = f2bf(a.z); p.w = f2bf(a.w);
                    *(ushort4*)(dst + k) = p;
                }
            }
        }
    } else {
        const int nb = (b - 3072) * 4 + (tid >> 6);
        const int l  = tid & 63;
        const unsigned long long b0 = __ballot(scores[(long)nb * KBlk + l] > THRESH);
        const unsigned long long b1 = __ballot(scores[(long)nb * KBlk + 64 + l] > THRESH);
        if (l == 0) { mbits[nb * 2] = b0; mbits[nb * 2 + 1] = b1; }
    }
}

// ---------------- main GEMM ----------------

__device__ __forceinline__ unsigned long long rfl64(unsigned long long v) {
    unsigned lo = __builtin_amdgcn_readfirstlane((unsigned)v);
    unsigned hi = __builtin_amdgcn_readfirstlane((unsigned)(v >> 32));
    return ((unsigned long long)hi << 32) | lo;
}

#define GLL16(g, l) __builtin_amdgcn_global_load_lds( \
    (const __attribute__((address_space(1))) void*)(g), \
    (__attribute__((address_space(3))) void*)(l), 16, 0, 0)

// pair bits (k32 blocks 2t, 2t+1) for wave-nb word pair (lo,hi)
#define PB2(np, t) ((unsigned)((((t) & 32) ? ((np) ? w1hi : w0hi) : ((np) ? w1lo : w0lo)) \
                               >> (2 * ((t) & 31))) & 3u)

// LDS fragment reads. Slot s of row p holds chunk s^(p&7); row&7 == lane&7 == cx,
// so reading slot (kq|kk<<2)^cx yields chunk kq|kk<<2 (k-quarter kq of k32-half kk).
#define ARD(BO, MH, i, kk) (*(const bf16x8*)(lds + (BO) + ((MH) << 14) + \
    (arb + (i) * 16 + fr) * 128 + ((((kq) | ((kk) << 2)) ^ cx) << 4)))
#define BRD(BO, np, j, kk) (*(const bf16x8*)(lds + (BO) + bkb + \
    (brb + ((np) * 2 + (j)) * 16 + fr) * 128 + ((((kq) | ((kk) << 2)) ^ cx) << 4)))

#define MFMAS(MH) \
    if (pa & 1u) { _Pragma("unroll") for (int i = 0; i < 4; ++i) { \
        acc[(MH)*4+i][0] = __builtin_amdgcn_mfma_f32_16x16x32_bf16(a0[i], b0[0], acc[(MH)*4+i][0], 0,0,0); \
        acc[(MH)*4+i][1] = __builtin_amdgcn_mfma_f32_16x16x32_bf16(a0[i], b0[1], acc[(MH)*4+i][1], 0,0,0); } } \
    if (pb & 1u) { _Pragma("unroll") for (int i = 0; i < 4; ++i) { \
        acc[(MH)*4+i][2] = __builtin_amdgcn_mfma_f32_16x16x32_bf16(a0[i], b0[2], acc[(MH)*4+i][2], 0,0,0); \
        acc[(MH)*4+i][3] = __builtin_amdgcn_mfma_f32_16x16x32_bf16(a0[i], b0[3], acc[(MH)*4+i][3], 0,0,0); } } \
    if (pa & 2u) { _Pragma("unroll") for (int i = 0; i < 4; ++i) { \
        acc[(MH)*4+i][0] = __builtin_amdgcn_mfma_f32_16x16x32_bf16(a1[i], b1[0], acc[(MH)*4+i][0], 0,0,0); \
        acc[(MH)*4+i][1] = __builtin_amdgcn_mfma_f32_16x16x32_bf16(a1[i], b1[1], acc[(MH)*4+i][1], 0,0,0); } } \
    if (pb & 2u) { _Pragma("unroll") for (int i = 0; i < 4; ++i) { \
        acc[(MH)*4+i][2] = __builtin_amdgcn_mfma_f32_16x16x32_bf16(a1[i], b1[2], acc[(MH)*4+i][2], 0,0,0); \
        acc[(MH)*4+i][3] = __builtin_amdgcn_mfma_f32_16x16x32_bf16(a1[i], b1[3], acc[(MH)*4+i][3], 0,0,0); } }

__global__ __launch_bounds__(512, 2)
void mpl_2ph(const unsigned short* __restrict__ Xb,   // [M,K] bf16
             const unsigned short* __restrict__ Wb,   // [N,K] bf16 (masked blocks stale/unused)
             const float* __restrict__ bias,
             const unsigned long long* __restrict__ mb, // [N/32][2]
             float* __restrict__ out, int M, int N, int K)
{
    // LDS: 2 bufs x 4 kinds x 16 KB = 128 KB. half-tile (kind) = 128 rows x 128 B.
    // kind0: A rows {0..63}u{128..191}   kind1: A rows {64..127}u{192..255}
    // kind2: B rows [0,128)              kind3: B rows [128,256)
    extern __shared__ __attribute__((aligned(16))) char lds[];

    const int tid  = threadIdx.x;
    const int lane = tid & 63;
    const int wave = tid >> 6;
    const int n0   = blockIdx.x * 256;
    const int m0   = blockIdx.y * 256;
    const long K2  = (long)K * 2;
    const int NT   = K >> 6;

    const int wm = (wave >> 2) * 128;
    const int wn = (wave & 3) * 64;

    // wave's two nb mask word pairs (scalarized)
    const int nbw = (n0 >> 5) + (wave & 3) * 2;
    const unsigned long long w0lo = rfl64(mb[nbw * 2]);
    const unsigned long long w0hi = rfl64(mb[nbw * 2 + 1]);
    const unsigned long long w1lo = rfl64(mb[(nbw + 1) * 2]);
    const unsigned long long w1hi = rfl64(mb[(nbw + 1) * 2 + 1]);

    f32x4 acc[8][4];
#pragma unroll
    for (int i = 0; i < 8; i++)
#pragma unroll
        for (int j = 0; j < 4; j++)
            acc[i][j] = (f32x4){0.f, 0.f, 0.f, 0.f};

    // staging geometry: wave covers LDS rows wave*8 + (lane>>3) (+64 for 2nd GLL),
    // slot lane&7; global source pre-swizzled: chunk = (lane&7) ^ (lane>>3).
    const int r0   = wave * 8 + (lane >> 3);
    const int cswz = ((lane & 7) ^ (lane >> 3)) * 16;
    const char* gA = (const char*)Xb + (long)(m0 + r0) * K2 + cswz;
    const char* gB = (const char*)Wb + (long)(n0 + r0) * K2 + cswz;
    const int ldso = wave * 1024;

    auto STAGEH = [&](int h) {
        const int t = h >> 2, kind = h & 3;
        char* l = lds + ((t & 1) << 16) + (kind << 14) + ldso;
        const long kbyte = (long)t * 128;
        if (kind < 2) {               // A: rows kind*64 + {0,128}
            const char* g = gA + (long)(kind * 64) * K2 + kbyte;
            GLL16(g, l);
            GLL16(g + 128 * K2, l + 8192);
        } else {                      // B: rows (kind&1)*128 + {0,64}
            const char* g = gB + (long)((kind & 1) * 128) * K2 + kbyte;
            GLL16(g, l);
            GLL16(g + 64 * K2, l + 8192);
        }
    };

    // fragment geometry
    const int fr  = lane & 15;
    const int kq  = lane >> 4;
    const int cx  = lane & 7;
    const int arb = (wave >> 2) * 64;                    // A LDS-row base
    const int bkb = 32768 + ((wave & 3) >> 1) * 16384;   // B kind base (kind2/3)
    const int brb = (wave & 1) * 64;                     // B LDS-row base

    // prologue: t0 all 4 kinds (8 loads) + t1.{k0,k2,k3} (6 loads)
    STAGEH(0); STAGEH(1); STAGEH(2); STAGEH(3);
    STAGEH(4); STAGEH(6); STAGEH(7);
    asm volatile("s_waitcnt vmcnt(6)" ::: "memory");   // t0's 8 landed
    __builtin_amdgcn_s_barrier();

    for (int t = 0; t < NT; ++t) {
        const int bo = (t & 1) << 16;
        const unsigned pa = PB2(0, t), pb = PB2(1, t);
        const unsigned anyk = pa | pb;
        bf16x8 a0[4], a1[4], b0[4], b1[4];

        // ---- phase 0: A half mh=0 + ALL B (B kept in regs for phase 1) ----
        if (anyk & 1u) {
#pragma unroll
            for (int i = 0; i < 4; ++i) a0[i] = ARD(bo, 0, i, 0);
        }
        if (anyk & 2u) {
#pragma unroll
            for (int i = 0; i < 4; ++i) a1[i] = ARD(bo, 0, i, 1);
        }
        if (pa & 1u) { b0[0] = BRD(bo, 0, 0, 0); b0[1] = BRD(bo, 0, 1, 0); }
        if (pa & 2u) { b1[0] = BRD(bo, 0, 0, 1); b1[1] = BRD(bo, 0, 1, 1); }
        if (pb & 1u) { b0[2] = BRD(bo, 1, 0, 0); b0[3] = BRD(bo, 1, 1, 0); }
        if (pb & 2u) { b1[2] = BRD(bo, 1, 0, 1); b1[3] = BRD(bo, 1, 1, 1); }
        if (t + 1 < NT) STAGEH(4 * (t + 1) + 1);       // k1 -> other buffer
        if (t < NT - 1) asm volatile("s_waitcnt vmcnt(8)" ::: "memory");
        else            asm volatile("s_waitcnt vmcnt(0)" ::: "memory");
        __builtin_amdgcn_s_barrier();
        asm volatile("s_waitcnt lgkmcnt(0)" ::: "memory");
        __builtin_amdgcn_sched_barrier(0);
        __builtin_amdgcn_s_setprio(1);
        MFMAS(0)
        __builtin_amdgcn_s_setprio(0);
        __builtin_amdgcn_s_barrier();

        // ---- phase 1: A half mh=1, B reused from registers ----
        if (anyk & 1u) {
#pragma unroll
            for (int i = 0; i < 4; ++i) a0[i] = ARD(bo, 1, i, 0);
        }
        if (anyk & 2u) {
#pragma unroll
            for (int i = 0; i < 4; ++i) a1[i] = ARD(bo, 1, i, 1);
        }
        if (t + 2 < NT) {                               // k0,k2,k3 -> same buffer
            STAGEH(4 * (t + 2) + 0);
            STAGEH(4 * (t + 2) + 2);
            STAGEH(4 * (t + 2) + 3);
        }
        if (t < NT - 2)      asm volatile("s_waitcnt vmcnt(8)" ::: "memory");
        else if (t == NT - 2) asm volatile("s_waitcnt vmcnt(2)" ::: "memory");
        __builtin_amdgcn_s_barrier();
        asm volatile("s_waitcnt lgkmcnt(0)" ::: "memory");
        __builtin_amdgcn_sched_barrier(0);
        __builtin_amdgcn_s_setprio(1);
        MFMAS(1)
        __builtin_amdgcn_s_setprio(0);
        __builtin_amdgcn_s_barrier();
    }

    // epilogue: C/D col=lane&15 (n), row=(lane>>4)*4+reg (m)
    const int cn = lane & 15;
    const int rq = (lane >> 4) * 4;
#pragma unroll
    for (int ni = 0; ni < 4; ni++) {
        const int n = n0 + wn + ni * 16 + cn;
        const float bv = bias[n];
#pragma unroll
        for (int mi = 0; mi < 8; mi++) {
#pragma unroll
            for (int r = 0; r < 4; r++) {
                const int m = m0 + wm + mi * 16 + rq + r;
                out[(long)m * N + n] = acc[mi][ni][r] + bv;
            }
        }
    }
}

// ---------------- fallback (R1 kernel) ----------------

#define FBM 128
#define FBN 128
#define FBK 32
#define LDSS (FBK + 8)
__global__ __launch_bounds__(256, 2)
void mpl_gemm_fb(const float* __restrict__ X, const float* __restrict__ W,
                 const float* __restrict__ bias, const float* __restrict__ scores,
                 float* __restrict__ out, int M, int N, int K)
{
    __shared__ unsigned short sA[FBM * LDSS];
    __shared__ unsigned short sB[FBN * LDSS];
    const int tid = threadIdx.x;
    const int m0 = blockIdx.y * FBM, n0 = blockIdx.x * FBN;
    const int wave = tid >> 6, lane = tid & 63;
    const int wm = (wave & 1) * 64, wn = (wave >> 1) * 64;
    const int kblocks = K >> 5;
    f32x4 acc[4][4];
#pragma unroll
    for (int i = 0; i < 4; i++)
#pragma unroll
        for (int j = 0; j < 4; j++) acc[i][j] = (f32x4){0.f, 0.f, 0.f, 0.f};
    int srow[4], sc4[4], snb[4];
#pragma unroll
    for (int i = 0; i < 4; i++) {
        int f = tid + 256 * i;
        srow[i] = f >> 3; sc4[i] = f & 7; snb[i] = (n0 + srow[i]) >> 5;
    }
    for (int k0 = 0; k0 < K; k0 += FBK) {
        const int kb = k0 >> 5;
#pragma unroll
        for (int i = 0; i < 4; i++) {
            const float4 v = *(const float4*)(X + (long)(m0 + srow[i]) * K + k0 + sc4[i] * 4);
            ushort4 p; p.x = f2bf(v.x); p.y = f2bf(v.y); p.z = f2bf(v.z); p.w = f2bf(v.w);
            *(ushort4*)&sA[srow[i] * LDSS + sc4[i] * 4] = p;
        }
#pragma unroll
        for (int i = 0; i < 4; i++) {
            const float msk = (scores[snb[i] * kblocks + kb] > THRESH) ? 1.0f : 0.0f;
            const float4 v = *(const float4*)(W + (long)(n0 + srow[i]) * K + k0 + sc4[i] * 4);
            ushort4 p; p.x = f2bf(v.x*msk); p.y = f2bf(v.y*msk); p.z = f2bf(v.z*msk); p.w = f2bf(v.w*msk);
            *(ushort4*)&sB[srow[i] * LDSS + sc4[i] * 4] = p;
        }
        __syncthreads();
        const int fr = lane & 15, kqf = (lane >> 4) * 8;
        bf16x8 af[4], bfr[4];
#pragma unroll
        for (int mi = 0; mi < 4; mi++) af[mi] = *(const bf16x8*)&sA[(wm + mi*16 + fr) * LDSS + kqf];
#pragma unroll
        for (int ni = 0; ni < 4; ni++) bfr[ni] = *(const bf16x8*)&sB[(wn + ni*16 + fr) * LDSS + kqf];
#pragma unroll
        for (int mi = 0; mi < 4; mi++)
#pragma unroll
            for (int ni = 0; ni < 4; ni++)
                acc[mi][ni] = __builtin_amdgcn_mfma_f32_16x16x32_bf16(af[mi], bfr[ni], acc[mi][ni], 0, 0, 0);
        __syncthreads();
    }
    const int cn = lane & 15, rq = (lane >> 4) * 4;
#pragma unroll
    for (int ni = 0; ni < 4; ni++) {
        const int n = n0 + wn + ni * 16 + cn;
        const float b = bias[n];
#pragma unroll
        for (int mi = 0; mi < 4; mi++)
#pragma unroll
            for (int r = 0; r < 4; r++)
                out[(long)(m0 + wm + mi*16 + rq + r) * N + n] = acc[mi][ni][r] + b;
    }
}

extern "C" void kernel_launch(void* const* d_in, const int* in_sizes, int n_in,
                              void* d_out, int out_size, void* d_ws, size_t ws_size,
                              hipStream_t stream) {
    const float* X      = (const float*)d_in[0];
    const float* W      = (const float*)d_in[1];
    const float* bias   = (const float*)d_in[2];
    const float* scores = (const float*)d_in[3];
    float* out          = (float*)d_out;

    const int N = in_sizes[2];            // 4096
    const int K = in_sizes[1] / N;        // 4096
    const int M = in_sizes[0] / K;        // 8192
    const int KB = K >> 5;                // 128
    const int NB = N >> 5;                // 128

    const size_t mk2 = (size_t)M * K * 2;
    const size_t nk2 = (size_t)N * K * 2;
    const size_t need = mk2 + nk2 + (size_t)NB * 16;

    if (ws_size >= need && KB == 128 && (M % 256) == 0 && (N % 256) == 0 &&
        (K % 1024) == 0 && (K >> 6) >= 3 && (NB % 4) == 0) {
        unsigned short* Xb = (unsigned short*)d_ws;
        unsigned short* Wb = (unsigned short*)((char*)d_ws + mk2);
        unsigned long long* mbits = (unsigned long long*)((char*)d_ws + mk2 + nk2);

        static int attr_set = 0;
        if (!attr_set) {
            hipFuncSetAttribute(reinterpret_cast<const void*>(mpl_2ph),
                                hipFuncAttributeMaxDynamicSharedMemorySize, 131072);
            attr_set = 1;
        }

        prep<<<3072 + NB / 4, 256, 0, stream>>>(X, W, scores, Xb, Wb, mbits, M, N, K);

        dim3 grid(N / 256, M / 256);
        mpl_2ph<<<grid, dim3(512), 131072, stream>>>(Xb, Wb, bias, mbits, out, M, N, K);
    } else {
        dim3 grid(N / FBN, M / FBM);
        mpl_gemm_fb<<<grid, dim3(256), 0, stream>>>(X, W, bias, scores, out, M, N, K);
    }
}